// Round 4
// baseline (556.817 us; speedup 1.0000x reference)
//
#include <hip/hip_runtime.h>
#include <cstdint>

#define NQ 20
#define DIM (1u << NQ)
#define NBLK 256u

// ================= constexpr GF(2) machinery =================
// Gray map g(x)=x^(x>>1) accumulates per CNOT-chain layer. Gate (l,b) is a
// butterfly with mask m=g^l(e_b) (span [b-l,b]) and selector parity(j&R),
// R = row b of g^{-l}. Final output gather: logical[i] = buf[i ^ (i>>4)].
constexpr unsigned cpair_mask(int l, int b) {
    unsigned m = 1u << b;
    for (int k = 0; k < l; ++k) m ^= m >> 1;
    return m;
}
constexpr unsigned cginv1(unsigned x) {
    x ^= x >> 1; x ^= x >> 2; x ^= x >> 4; x ^= x >> 8; x ^= x >> 16;
    return x & 0xFFFFFu;
}
constexpr unsigned csel_mask(int l, int b) {
    unsigned R = 0;
    for (int k = 0; k < NQ; ++k) {
        unsigned w = 1u << k;
        for (int t = 0; t < l; ++t) w = cginv1(w);
        if ((w >> b) & 1u) R |= 1u << k;
    }
    return R;
}
constexpr int cpopc(unsigned x) { int c = 0; while (x) { c += x & 1; x >>= 1; } return c; }

struct GateC { unsigned R; unsigned sb; int valid; int tix; };
struct GroupC { int pv[3]; unsigned gxs[8]; GateC gt[3]; };
struct SchedC { GroupC g[8]; int ng; };

constexpr void add_group(SchedC& s, int l0, int b0, int l1, int b1, int l2, int b2) {
    GroupC g{};
    int ls[3] = {l0, l1, l2}; int bs[3] = {b0, b1, b2};
    unsigned m[3] = {0, 0, 0};
    for (int j = 0; j < 3; ++j) {
        bool val = ls[j] >= 0;
        m[j] = val ? cpair_mask(ls[j], bs[j]) : (1u << bs[j]);   // dummy: plain bit
        g.gt[j].R = val ? csel_mask(ls[j], bs[j]) : 0u;
        g.gt[j].valid = val ? 1 : 0;
        g.gt[j].tix = val ? (ls[j] * NQ + bs[j]) : 0;            // global trig index
    }
    for (int e = 0; e < 8; ++e) {
        unsigned x = 0;
        for (int j = 0; j < 3; ++j) if ((e >> j) & 1) x ^= m[j];
        g.gxs[e] = x;
    }
    for (int j = 0; j < 3; ++j) {
        unsigned sb = 0;
        for (int e = 0; e < 8; ++e) if (cpopc(g.gxs[e] & g.gt[j].R) & 1) sb |= (1u << e);
        g.gt[j].sb = sb;
    }
    int pv[3] = {0, 0, 0};
    for (int j = 0; j < 3; ++j) { int p = 0; for (int k = 0; k < NQ; ++k) if ((m[j] >> k) & 1) p = k; pv[j] = p; }
    for (int a = 0; a < 2; ++a)
        for (int c = 0; c < 2 - a; ++c)
            if (pv[c] > pv[c + 1]) { int t = pv[c]; pv[c] = pv[c + 1]; pv[c + 1] = t; }
    g.pv[0] = pv[0]; g.pv[1] = pv[1]; g.pv[2] = pv[2];
    s.g[s.ng] = g; s.ng++;
}

constexpr SchedC mk_sched(int kid) {
    SchedC s{};
    if (kid == 0) {                                  // P1: l0 b0..11
        for (int b = 0; b < 12; b += 3) add_group(s, 0, b, 0, b + 1, 0, b + 2);
    } else if (kid == 1) {                           // P2: l0 b12..19, l1 b12..19
        add_group(s, 0, 12, 0, 13, 0, 14);
        add_group(s, 0, 15, 0, 16, 0, 17);
        add_group(s, 0, 18, 0, 19, 1, 12);
        add_group(s, 1, 13, 1, 14, 1, 15);
        add_group(s, 1, 16, 1, 17, 1, 18);
        add_group(s, 1, 19, -1, 17, -1, 18);         // 2 identity pads
    } else if (kid == 2) {                           // P3: l1 b0..11, l2 b0..11
        for (int b = 0; b < 12; b += 3) add_group(s, 1, b, 1, b + 1, 1, b + 2);
        for (int b = 0; b < 12; b += 3) add_group(s, 2, b, 2, b + 1, 2, b + 2);
    } else if (kid == 3) {                           // P4: l2 b12..19, l3 b13..19
        add_group(s, 2, 12, 2, 13, 2, 14);
        add_group(s, 2, 15, 2, 16, 2, 17);
        add_group(s, 2, 18, 2, 19, 3, 13);
        add_group(s, 3, 14, 3, 15, 3, 16);
        add_group(s, 3, 17, 3, 18, 3, 19);
    } else {                                         // P5: l3 b0..11
        for (int b = 0; b < 12; b += 3) add_group(s, 3, b, 3, b + 1, 3, b + 2);
    }
    return s;
}

// LDS swizzle (involution, linear): keeps group ds ops near the 4-slot min.
__device__ __forceinline__ unsigned swz(unsigned t) { return t ^ ((t >> 5) & 0xFu); }
constexpr unsigned cswz(unsigned t) { return t ^ ((t >> 5) & 0xFu); }

template<int LO>
__device__ __forceinline__ unsigned gmap(unsigned t, unsigned mid) {
    if constexpr (LO == 12) return (mid << 12) | t;
    else return ((t >> LO) << (LO + 8)) | (mid << LO) | (t & ((1u << LO) - 1u));
}

// ================= one gate phase (device) =================
// 4096-amp tile in LDS; 512 threads x 8-amp cosets; 3 gates per LDS round.
template<int KID, int LO, bool INIT>
__device__ void phase_gates(float2* __restrict__ st,
                            const float* __restrict__ qr,
                            const float* __restrict__ qi,
                            const float2* __restrict__ trigS,
                            float2* __restrict__ lds) {
    constexpr SchedC S = mk_sched(KID);
    constexpr int SHIFT = (LO == 12) ? 0 : 8;
    float4* lds4 = reinterpret_cast<float4*>(lds);
    const unsigned tid = threadIdx.x;
    const unsigned mid = blockIdx.x;

    // ---- stage in ----
    if (INIT) {
        const float4* r4 = reinterpret_cast<const float4*>(qr);
        const float4* i4 = reinterpret_cast<const float4*>(qi);
#pragma unroll
        for (int k = 0; k < 2; ++k) {
            unsigned u4 = tid + (unsigned)(k << 9);          // float4-of-float = 4 amps
            float4 r = r4[(mid << 10) + u4], im = i4[(mid << 10) + u4];
            unsigned t = u4 << 2;
            unsigned sw = swz(t);
            unsigned b4 = sw & ~3u, lo2 = sw & 3u;
            lds[b4 | (0u ^ lo2)] = make_float2(r.x, im.x);
            lds[b4 | (1u ^ lo2)] = make_float2(r.y, im.y);
            lds[b4 | (2u ^ lo2)] = make_float2(r.z, im.z);
            lds[b4 | (3u ^ lo2)] = make_float2(r.w, im.w);
        }
    } else {
        const float4* s4 = reinterpret_cast<const float4*>(st);
#pragma unroll
        for (int k = 0; k < 4; ++k) {
            unsigned u4 = tid + (unsigned)(k << 9);          // float4-of-float2 = 2 amps
            unsigned t = u4 << 1;
            unsigned g = gmap<LO>(t, mid);
            float4 d = s4[g >> 1];
            unsigned sw = swz(t);
            float4 e = (sw & 1u) ? make_float4(d.z, d.w, d.x, d.y) : d;
            lds4[sw >> 1] = e;
        }
    }
    __syncthreads();

    // ---- gate groups ----
#pragma unroll
    for (int gi = 0; gi < S.ng; ++gi) {
        unsigned t0 = tid;
        {
            const unsigned p0 = (unsigned)(S.g[gi].pv[0] - SHIFT);
            t0 = ((t0 >> p0) << (p0 + 1)) | (t0 & ((1u << p0) - 1u));
            const unsigned p1 = (unsigned)(S.g[gi].pv[1] - SHIFT);
            t0 = ((t0 >> p1) << (p1 + 1)) | (t0 & ((1u << p1) - 1u));
            const unsigned p2 = (unsigned)(S.g[gi].pv[2] - SHIFT);
            t0 = ((t0 >> p2) << (p2 + 1)) | (t0 & ((1u << p2) - 1u));
        }
        const unsigned g0 = gmap<LO>(t0, mid);     // global index of coset base
        const unsigned sz0 = swz(t0);

        float2 v[8]; unsigned ad[8];
#pragma unroll
        for (int e = 0; e < 8; ++e) {
            const unsigned lx = S.g[gi].gxs[e] >> SHIFT;
            ad[e] = sz0 ^ cswz(lx);                // cswz(lx) folds to an immediate
            v[e] = lds[ad[e]];
        }
#pragma unroll
        for (int j = 0; j < 3; ++j) {
            if (S.g[gi].gt[j].valid) {
                const float2 cs = trigS[S.g[gi].gt[j].tix];
                const float c = cs.x, s = cs.y;
                const unsigned par = (unsigned)__popc(g0 & S.g[gi].gt[j].R) & 1u;
                const float sp = par ? s : -s;     // sigma when sb-bit = 0
                const float sn = -sp;              // sigma when sb-bit = 1
#pragma unroll
                for (int pr = 0; pr < 4; ++pr) {
                    constexpr int BASE[3][4] = {{0, 2, 4, 6}, {0, 1, 4, 5}, {0, 1, 2, 3}};
                    const int ea = BASE[j][pr];
                    const int eb = ea | (1 << j);
                    const float sg = ((S.g[gi].gt[j].sb >> ea) & 1u) ? sn : sp;
                    const float2 a = v[ea], b = v[eb];
                    v[ea] = make_float2(c * a.x + sg * b.x, c * a.y + sg * b.y);
                    v[eb] = make_float2(c * b.x - sg * a.x, c * b.y - sg * a.y);
                }
            }
        }
#pragma unroll
        for (int e = 0; e < 8; ++e) lds[ad[e]] = v[e];
        __syncthreads();
    }

    // ---- stage out ----
    float4* s4o = reinterpret_cast<float4*>(st);
#pragma unroll
    for (int k = 0; k < 4; ++k) {
        unsigned u4 = tid + (unsigned)(k << 9);
        unsigned t = u4 << 1;
        unsigned g = gmap<LO>(t, mid);
        unsigned sw = swz(t);
        float4 e = lds4[sw >> 1];
        float4 d = (sw & 1u) ? make_float4(e.z, e.w, e.x, e.y) : e;
        s4o[g >> 1] = d;
    }
}

// ================= final phase: gate (3,12) + inverse-gray gather =================
__device__ void phase_final(const float2* __restrict__ st,
                            float* __restrict__ out,
                            const float2* __restrict__ trigS) {
    constexpr unsigned FM = cpair_mask(3, 12);     // 0x1E00 (bits 9..12)
    constexpr unsigned FR = csel_mask(3, 12);      // bits >= 12 only
    const float2 cs = trigS[3 * NQ + 12];
    const float c = cs.x, s = cs.y;
    const unsigned gid = blockIdx.x * 512u + threadIdx.x;   // 131072 threads
#pragma unroll
    for (int k = 0; k < 4; ++k) {
        unsigned u = gid + (unsigned)(k << 17);             // [0, 2^19) pair index
        unsigned j0 = ((u >> 12) << 13) | (u & 0xFFFu);     // bit12 = 0 coset rep
        unsigned j1 = j0 ^ FM;
        float2 a = st[j0], b = st[j1];
        unsigned sel = (unsigned)__popc(j0 & FR) & 1u;
        float sg = sel ? s : -s;
        float2 o0 = make_float2(c * a.x + sg * b.x, c * a.y + sg * b.y);
        float2 o1 = make_float2(c * b.x - sg * a.x, c * b.y - sg * a.y);
        unsigned i0 = j0 ^ (j0 >> 4) ^ (j0 >> 8) ^ (j0 >> 12) ^ (j0 >> 16);
        unsigned i1 = j1 ^ (j1 >> 4) ^ (j1 >> 8) ^ (j1 >> 12) ^ (j1 >> 16);
        out[i0] = o0.x; out[DIM + i0] = o0.y;
        out[i1] = o1.x; out[DIM + i1] = o1.y;
    }
}

// ================= grid sync (manual, capacity-guaranteed co-residency) =================
__device__ __forceinline__ void gsync(unsigned* cnt, unsigned target) {
    __syncthreads();
    __threadfence();                               // device-scope release (L2 wb)
    if (threadIdx.x == 0) {
        atomicAdd(cnt, 1u);                        // device-scope by default
        while (__hip_atomic_load(cnt, __ATOMIC_ACQUIRE, __HIP_MEMORY_SCOPE_AGENT) < target)
            __builtin_amdgcn_s_sleep(2);
    }
    __syncthreads();
    __threadfence();                               // device-scope acquire (L1/L2 inv)
}

// ================= persistent kernel =================
// 256 blocks x 512 threads; LDS 33 KB, VGPR capped at 128 -> >=2 blocks/CU
// capacity -> all 256 blocks co-resident under any packing (spin-safe).
__global__ __launch_bounds__(512, 4) void k_all(const float* __restrict__ theta,
                                                const float* __restrict__ qr,
                                                const float* __restrict__ qi,
                                                float2* __restrict__ st,
                                                float* __restrict__ out,
                                                unsigned* __restrict__ cnt) {
    __shared__ __align__(16) float2 lds[4096];
    __shared__ float2 trigS[80];
    const unsigned tid = threadIdx.x;
    if (tid < 80) {
        int l = tid / NQ, b = tid % NQ;
        float th = 0.5f * theta[l * NQ + (NQ - 1 - b)];
        trigS[tid] = make_float2(cosf(th), sinf(th));
    }
    // (trig visible after phase 1's internal __syncthreads, before first use)

    phase_gates<0, 12, true >(st, qr, qi, trigS, lds);
    gsync(cnt, 1 * NBLK);
    phase_gates<1,  3, false>(st, qr, qi, trigS, lds);
    gsync(cnt, 2 * NBLK);
    phase_gates<2, 12, false>(st, qr, qi, trigS, lds);
    gsync(cnt, 3 * NBLK);
    phase_gates<3,  2, false>(st, qr, qi, trigS, lds);
    gsync(cnt, 4 * NBLK);
    phase_gates<4, 12, false>(st, qr, qi, trigS, lds);
    gsync(cnt, 5 * NBLK);
    phase_final(st, out, trigS);
}

__global__ void k_reset(unsigned* cnt) { *cnt = 0u; }

// ================= launch =================
extern "C" void kernel_launch(void* const* d_in, const int* in_sizes, int n_in,
                              void* d_out, int out_size, void* d_ws, size_t ws_size,
                              hipStream_t stream) {
    const float* theta = (const float*)d_in[0];   // (4,20) float32
    const float* qr    = (const float*)d_in[1];
    const float* qi    = (const float*)d_in[2];
    float* out = (float*)d_out;
    float2* st = (float2*)d_ws;                                   // 8 MiB state
    unsigned* cnt = (unsigned*)((char*)d_ws + (size_t)(8u << 20));

    k_reset<<<1, 1, 0, stream>>>(cnt);
    k_all<<<NBLK, 512, 0, stream>>>(theta, qr, qi, st, out, cnt);
}

// Round 5
// 61.249 us; speedup vs baseline: 9.0910x; 9.0910x over previous
//
#include <hip/hip_runtime.h>
#include <cstdint>

#define NQ 20
#define DIM (1u << NQ)

typedef float f32x2 __attribute__((ext_vector_type(2)));
typedef float f32x4 __attribute__((ext_vector_type(4)));

// ================= constexpr GF(2) machinery =================
// Gray map g(x)=x^(x>>1) accumulates per CNOT-chain layer. Gate (l,b) is a
// butterfly with mask m=g^l(e_b) (span [b-l,b]) and selector parity(j&R),
// R = row b of g^{-l}. Final gather: out[ginv4(j)] = buf[j], g^4 = I+S^4.
constexpr unsigned cpair_mask(int l, int b) {
    unsigned m = 1u << b;
    for (int k = 0; k < l; ++k) m ^= m >> 1;
    return m;
}
constexpr unsigned cginv1(unsigned x) {
    x ^= x >> 1; x ^= x >> 2; x ^= x >> 4; x ^= x >> 8; x ^= x >> 16;
    return x & 0xFFFFFu;
}
constexpr unsigned csel_mask(int l, int b) {
    unsigned R = 0;
    for (int k = 0; k < NQ; ++k) {
        unsigned w = 1u << k;
        for (int t = 0; t < l; ++t) w = cginv1(w);
        if ((w >> b) & 1u) R |= 1u << k;
    }
    return R;
}
constexpr int cpopc(unsigned x) { int c = 0; while (x) { c += x & 1; x >>= 1; } return c; }

struct GateC { unsigned R; unsigned sb; int valid; int tix; };
struct GroupC { int pv[3]; unsigned gxs[8]; GateC gt[3]; };
struct SchedC { GroupC g[8]; int ng; };

constexpr void add_group(SchedC& s, int l0, int b0, int l1, int b1, int l2, int b2) {
    GroupC g{};
    int ls[3] = {l0, l1, l2}; int bs[3] = {b0, b1, b2};
    unsigned m[3] = {0, 0, 0};
    for (int j = 0; j < 3; ++j) {
        bool val = ls[j] >= 0;
        m[j] = val ? cpair_mask(ls[j], bs[j]) : (1u << bs[j]);   // dummy: plain bit
        g.gt[j].R = val ? csel_mask(ls[j], bs[j]) : 0u;
        g.gt[j].valid = val ? 1 : 0;
        g.gt[j].tix = val ? (ls[j] * NQ + bs[j]) : 0;            // trig index
    }
    for (int e = 0; e < 8; ++e) {
        unsigned x = 0;
        for (int j = 0; j < 3; ++j) if ((e >> j) & 1) x ^= m[j];
        g.gxs[e] = x;
    }
    for (int j = 0; j < 3; ++j) {
        unsigned sb = 0;
        for (int e = 0; e < 8; ++e) if (cpopc(g.gxs[e] & g.gt[j].R) & 1) sb |= (1u << e);
        g.gt[j].sb = sb;
    }
    int pv[3] = {0, 0, 0};
    for (int j = 0; j < 3; ++j) { int p = 0; for (int k = 0; k < NQ; ++k) if ((m[j] >> k) & 1) p = k; pv[j] = p; }
    for (int a = 0; a < 2; ++a)
        for (int c = 0; c < 2 - a; ++c)
            if (pv[c] > pv[c + 1]) { int t = pv[c]; pv[c] = pv[c + 1]; pv[c + 1] = t; }
    g.pv[0] = pv[0]; g.pv[1] = pv[1]; g.pv[2] = pv[2];
    s.g[s.ng] = g; s.ng++;
}

constexpr SchedC mk_sched(int kid) {
    SchedC s{};
    if (kid == 0) {                                  // P1: l0 b0..11
        for (int b = 0; b < 12; b += 3) add_group(s, 0, b, 0, b + 1, 0, b + 2);
    } else if (kid == 1) {                           // P2: l0 b12..19, l1 b12..19
        add_group(s, 0, 12, 0, 13, 0, 14);
        add_group(s, 0, 15, 0, 16, 0, 17);
        add_group(s, 0, 18, 0, 19, 1, 12);
        add_group(s, 1, 13, 1, 14, 1, 15);
        add_group(s, 1, 16, 1, 17, 1, 18);
        add_group(s, 1, 19, -1, 17, -1, 18);         // 2 identity pads
    } else if (kid == 2) {                           // P3: l1 b0..11, l2 b0..11
        for (int b = 0; b < 12; b += 3) add_group(s, 1, b, 1, b + 1, 1, b + 2);
        for (int b = 0; b < 12; b += 3) add_group(s, 2, b, 2, b + 1, 2, b + 2);
    } else if (kid == 3) {                           // P4: l2 b12..19, l3 b13..19
        add_group(s, 2, 12, 2, 13, 2, 14);
        add_group(s, 2, 15, 2, 16, 2, 17);
        add_group(s, 2, 18, 2, 19, 3, 13);
        add_group(s, 3, 14, 3, 15, 3, 16);
        add_group(s, 3, 17, 3, 18, 3, 19);
    } else {                                         // P5: l3 b0..11  (+(3,12) fused at stage-in)
        for (int b = 0; b < 12; b += 3) add_group(s, 3, b, 3, b + 1, 3, b + 2);
    }
    return s;
}

// LDS swizzle (involution, linear)
__device__ __forceinline__ unsigned swz(unsigned t) { return t ^ ((t >> 5) & 0xFu); }
constexpr unsigned cswz(unsigned t) { return t ^ ((t >> 5) & 0xFu); }

template<int LO>
__device__ __forceinline__ unsigned gmap(unsigned t, unsigned mid) {
    if constexpr (LO == 12) return (mid << 12) | t;
    else return ((t >> LO) << (LO + 8)) | (mid << LO) | (t & ((1u << LO) - 1u));
}

__device__ __forceinline__ f32x2 splat2(float x) { f32x2 r = {x, x}; return r; }
__device__ __forceinline__ f32x4 splat4(float x) { f32x4 r = {x, x, x, x}; return r; }

// ================= gate kernel =================
// 4096-amp LDS tile; 512 threads x 8-amp cosets; 3 gates per LDS round.
// MODE: 0 = normal (st->st), 1 = init (q0->st), 2 = final (st + (3,12) -> out scatter)
template<int KID, int LO, int MODE>
__global__ __launch_bounds__(512) void k_gates(f32x4* __restrict__ st,
                                               const float* __restrict__ qr,
                                               const float* __restrict__ qi,
                                               const float* __restrict__ theta,
                                               float* __restrict__ out) {
    constexpr SchedC S = mk_sched(KID);
    constexpr int SHIFT = (LO == 12) ? 0 : 8;
    __shared__ __align__(16) f32x2 lds[4096];
    __shared__ float2 trigS[80];
    f32x4* lds4 = reinterpret_cast<f32x4*>(lds);
    const unsigned tid = threadIdx.x;
    const unsigned mid = blockIdx.x;

    if (tid < 80) {
        int l = tid / NQ, b = tid % NQ;
        float th = 0.5f * theta[l * NQ + (NQ - 1 - b)];
        trigS[tid] = make_float2(cosf(th), sinf(th));
    }

    // ---- stage in ----
    if constexpr (MODE == 1) {
        const f32x4* r4 = reinterpret_cast<const f32x4*>(qr);
        const f32x4* i4 = reinterpret_cast<const f32x4*>(qi);
#pragma unroll
        for (int k = 0; k < 2; ++k) {
            unsigned u4 = tid + (unsigned)(k << 9);          // 4 amps (planar)
            f32x4 r = r4[(mid << 10) + u4], im = i4[(mid << 10) + u4];
            unsigned t = u4 << 2;
            unsigned sw = swz(t);
            unsigned b4 = sw & ~3u, lo2 = sw & 3u;
            lds[b4 | (0u ^ lo2)] = f32x2{r.x, im.x};
            lds[b4 | (1u ^ lo2)] = f32x2{r.y, im.y};
            lds[b4 | (2u ^ lo2)] = f32x2{r.z, im.z};
            lds[b4 | (3u ^ lo2)] = f32x2{r.w, im.w};
        }
    } else if constexpr (MODE == 0) {
#pragma unroll
        for (int k = 0; k < 4; ++k) {
            unsigned u4 = tid + (unsigned)(k << 9);          // 2 amps (interleaved)
            unsigned t = u4 << 1;
            unsigned g = gmap<LO>(t, mid);
            f32x4 d = st[g >> 1];
            unsigned sw = swz(t);
            f32x4 e = (sw & 1u) ? __builtin_shufflevector(d, d, 2, 3, 0, 1) : d;
            lds4[sw >> 1] = e;
        }
    } else {
        // P5 stage-in with fused gate (3,12): out[g] = c*old[g] + sgn*old[g^FM],
        // sgn = (popc(g&FR)&1 ? s : -s); FR has bits >=12 only -> block-uniform.
        constexpr unsigned FM = cpair_mask(3, 12);           // 0x1E00
        constexpr unsigned FR = csel_mask(3, 12);            // bits >= 12 only
        const float thF = 0.5f * theta[3 * NQ + (NQ - 1 - 12)];
        const float cF = cosf(thF), sF = sinf(thF);
        const float sgn = ((unsigned)__popc((mid << 12) & FR) & 1u) ? sF : -sF;
        const f32x4 cv = splat4(cF), sv = splat4(sgn);
#pragma unroll
        for (int k = 0; k < 4; ++k) {
            unsigned u4 = tid + (unsigned)(k << 9);
            unsigned t = u4 << 1;
            unsigned g = (mid << 12) | t;
            f32x4 A = st[g >> 1];
            f32x4 B = st[(g ^ FM) >> 1];                     // FM even -> aligned
            f32x4 d = cv * A + sv * B;
            unsigned sw = swz(t);
            f32x4 e = (sw & 1u) ? __builtin_shufflevector(d, d, 2, 3, 0, 1) : d;
            lds4[sw >> 1] = e;
        }
    }
    __syncthreads();

    // ---- gate groups ----
#pragma unroll
    for (int gi = 0; gi < S.ng; ++gi) {
        unsigned t0 = tid;
        {
            const unsigned p0 = (unsigned)(S.g[gi].pv[0] - SHIFT);
            t0 = ((t0 >> p0) << (p0 + 1)) | (t0 & ((1u << p0) - 1u));
            const unsigned p1 = (unsigned)(S.g[gi].pv[1] - SHIFT);
            t0 = ((t0 >> p1) << (p1 + 1)) | (t0 & ((1u << p1) - 1u));
            const unsigned p2 = (unsigned)(S.g[gi].pv[2] - SHIFT);
            t0 = ((t0 >> p2) << (p2 + 1)) | (t0 & ((1u << p2) - 1u));
        }
        const unsigned g0 = gmap<LO>(t0, mid);     // global index of coset base
        const unsigned sz0 = swz(t0);

        f32x2 v[8]; unsigned ad[8];
#pragma unroll
        for (int e = 0; e < 8; ++e) {
            const unsigned lx = S.g[gi].gxs[e] >> SHIFT;
            ad[e] = sz0 ^ cswz(lx);                // cswz(lx) folds to an immediate
            v[e] = lds[ad[e]];
        }
#pragma unroll
        for (int j = 0; j < 3; ++j) {
            if (S.g[gi].gt[j].valid) {
                const float2 cs = trigS[S.g[gi].gt[j].tix];
                const f32x2 cc = splat2(cs.x);
                const unsigned par = (unsigned)__popc(g0 & S.g[gi].gt[j].R) & 1u;
                const float sp = par ? cs.y : -cs.y;   // sigma when sb-bit = 0
#pragma unroll
                for (int pr = 0; pr < 4; ++pr) {
                    constexpr int BASE[3][4] = {{0, 2, 4, 6}, {0, 1, 4, 5}, {0, 1, 2, 3}};
                    const int ea = BASE[j][pr];
                    const int eb = ea | (1 << j);
                    const f32x2 sg = splat2(((S.g[gi].gt[j].sb >> ea) & 1u) ? -sp : sp);
                    const f32x2 a = v[ea], b = v[eb];
                    v[ea] = cc * a + sg * b;           // v_pk_fma_f32 pair
                    v[eb] = cc * b - sg * a;
                }
            }
        }
#pragma unroll
        for (int e = 0; e < 8; ++e) lds[ad[e]] = v[e];
        __syncthreads();
    }

    // ---- stage out ----
    if constexpr (MODE != 2) {
#pragma unroll
        for (int k = 0; k < 4; ++k) {
            unsigned u4 = tid + (unsigned)(k << 9);
            unsigned t = u4 << 1;
            unsigned g = gmap<LO>(t, mid);
            unsigned sw = swz(t);
            f32x4 e = lds4[sw >> 1];
            f32x4 d = (sw & 1u) ? __builtin_shufflevector(e, e, 2, 3, 0, 1) : e;
            st[g >> 1] = d;
        }
    } else {
        // inverse-Gray scatter + planar split. amps (t,t+1) -> out (i, i^1).
        float2* outR = reinterpret_cast<float2*>(out);
        float2* outI = reinterpret_cast<float2*>(out + DIM);
#pragma unroll
        for (int k = 0; k < 4; ++k) {
            unsigned u4 = tid + (unsigned)(k << 9);
            unsigned t = u4 << 1;
            unsigned sw = swz(t);
            f32x4 e = lds4[sw >> 1];
            f32x4 d = (sw & 1u) ? __builtin_shufflevector(e, e, 2, 3, 0, 1) : e;
            unsigned g = (mid << 12) | t;
            unsigned i0 = g ^ (g >> 4) ^ (g >> 8) ^ (g >> 12) ^ (g >> 16);
            unsigned ib = i0 >> 1;
            float2 re, im;
            if (i0 & 1u) { re = make_float2(d.z, d.x); im = make_float2(d.w, d.y); }
            else         { re = make_float2(d.x, d.z); im = make_float2(d.y, d.w); }
            outR[ib] = re;
            outI[ib] = im;
        }
    }
}

// ================= launch =================
extern "C" void kernel_launch(void* const* d_in, const int* in_sizes, int n_in,
                              void* d_out, int out_size, void* d_ws, size_t ws_size,
                              hipStream_t stream) {
    const float* theta = (const float*)d_in[0];   // (4,20) float32
    const float* qr    = (const float*)d_in[1];
    const float* qi    = (const float*)d_in[2];
    float* out = (float*)d_out;
    f32x4* st = (f32x4*)d_ws;                     // 8 MiB interleaved state

    k_gates<0, 12, 1><<<256, 512, 0, stream>>>(st, qr, qi, theta, out);
    k_gates<1,  3, 0><<<256, 512, 0, stream>>>(st, qr, qi, theta, out);
    k_gates<2, 12, 0><<<256, 512, 0, stream>>>(st, qr, qi, theta, out);
    k_gates<3,  2, 0><<<256, 512, 0, stream>>>(st, qr, qi, theta, out);
    k_gates<4, 12, 2><<<256, 512, 0, stream>>>(st, qr, qi, theta, out);
}

// Round 6
// 60.724 us; speedup vs baseline: 9.1697x; 1.0087x over previous
//
#include <hip/hip_runtime.h>
#include <cstdint>

#define NQ 20
#define DIM (1u << NQ)

typedef float f32x2 __attribute__((ext_vector_type(2)));
typedef float f32x4 __attribute__((ext_vector_type(4)));

// ================= constexpr GF(2) machinery =================
// Gray map g(x)=x^(x>>1) accumulates per CNOT-chain layer. Gate (l,b) is a
// butterfly with mask m=g^l(e_b) (span [b-l,b]) and selector parity(j&R),
// R = row b of g^{-l}. Commutation rule (verified): G1,G2 commute iff
// parity(m1&R2) == parity(m2&R1). Final gather: out[ginv4(j)] = buf[j].
constexpr unsigned cpair_mask(int l, int b) {
    unsigned m = 1u << b;
    for (int k = 0; k < l; ++k) m ^= m >> 1;
    return m;
}
constexpr unsigned cginv1(unsigned x) {
    x ^= x >> 1; x ^= x >> 2; x ^= x >> 4; x ^= x >> 8; x ^= x >> 16;
    return x & 0xFFFFFu;
}
constexpr unsigned csel_mask(int l, int b) {
    unsigned R = 0;
    for (int k = 0; k < NQ; ++k) {
        unsigned w = 1u << k;
        for (int t = 0; t < l; ++t) w = cginv1(w);
        if ((w >> b) & 1u) R |= 1u << k;
    }
    return R;
}
constexpr int cpopc(unsigned x) { int c = 0; while (x) { c += x & 1; x >>= 1; } return c; }
constexpr unsigned cswz(unsigned t) { return t ^ ((t >> 5) & 0xFu); }

struct GateC { unsigned R; unsigned sb; int valid; int tix; int thix; };
struct GroupC { int pv[3]; unsigned gxs[8]; unsigned lgxs[8]; GateC gt[3]; };
struct SchedC { GroupC g[12]; int ng; };
struct PhC { SchedC s; int FL, GAP; };

// local tile bits: [0,FL) global-direct, [FL,12) map to global [FL+GAP, GAP+12)
constexpr unsigned to_local(unsigned m, int FL, int GAP) {
    return (m & ((1u << FL) - 1u)) | ((m >> (FL + GAP)) << FL);
}

constexpr void addg(SchedC& s, int FL, int GAP,
                    int l0, int b0, int l1, int b1, int l2, int b2) {
    GroupC g{};
    int ls[3] = {l0, l1, l2}; int bs[3] = {b0, b1, b2};
    unsigned m[3] = {0, 0, 0};
    for (int j = 0; j < 3; ++j) {
        bool val = ls[j] >= 0;
        m[j] = val ? cpair_mask(ls[j], bs[j]) : (1u << bs[j]);   // pad: plain bit
        g.gt[j].R = val ? csel_mask(ls[j], bs[j]) : 0u;
        g.gt[j].valid = val ? 1 : 0;
        g.gt[j].tix = val ? (ls[j] * NQ + bs[j]) : 0;
        g.gt[j].thix = val ? (ls[j] * NQ + (NQ - 1 - bs[j])) : 0;
    }
    for (int e = 0; e < 8; ++e) {
        unsigned x = 0;
        for (int j = 0; j < 3; ++j) if ((e >> j) & 1) x ^= m[j];
        g.gxs[e] = x;
        g.lgxs[e] = to_local(x, FL, GAP);
    }
    for (int j = 0; j < 3; ++j) {
        unsigned sb = 0;
        for (int e = 0; e < 8; ++e) if (cpopc(g.gxs[e] & g.gt[j].R) & 1) sb |= (1u << e);
        g.gt[j].sb = sb;
    }
    int pv[3] = {0, 0, 0};
    for (int j = 0; j < 3; ++j) {
        unsigned lm = to_local(m[j], FL, GAP);
        int p = 0; for (int k = 0; k < 12; ++k) if ((lm >> k) & 1) p = k;
        pv[j] = p;
    }
    for (int a = 0; a < 2; ++a)
        for (int c = 0; c < 2 - a; ++c)
            if (pv[c] > pv[c + 1]) { int t = pv[c]; pv[c] = pv[c + 1]; pv[c + 1] = t; }
    g.pv[0] = pv[0]; g.pv[1] = pv[1]; g.pv[2] = pv[2];
    s.g[s.ng] = g; s.ng++;
}

// 4-phase schedule (commutation-verified). Group 0 fuses into stage-in,
// group ng-1 fuses into stage-out.
constexpr PhC mk_phase(int ph) {
    PhC P{};
    if (ph == 0) {
        P.FL = 12; P.GAP = 8;                       // window [0,11]
        addg(P.s, 12, 8, 0,0, 0,1, 0,2);            // stage-in fused
        addg(P.s, 12, 8, 0,3, 0,4, 0,5);
        addg(P.s, 12, 8, 0,6, 0,7, 0,8);
        addg(P.s, 12, 8, 0,9, 0,10, 0,11);          // stage-out fused
    } else if (ph == 1) {
        P.FL = 4; P.GAP = 8;                        // window [12,19], 128B rows
        addg(P.s, 4, 8, 0,12, 0,13, 0,14);          // stage-in fused
        addg(P.s, 4, 8, 0,15, 0,16, 0,17);
        addg(P.s, 4, 8, 0,18, 0,19, 1,13);
        addg(P.s, 4, 8, 1,14, 1,15, 1,16);
        addg(P.s, 4, 8, 1,17, 1,18, 1,19);
        addg(P.s, 4, 8, 2,14, 2,15, 2,16);
        addg(P.s, 4, 8, 2,17, 2,18, 2,19);
        addg(P.s, 4, 8, 3,15, 3,16, 3,17);
        addg(P.s, 4, 8, 3,18, 3,19, -1,0);          // stage-out fused (1 pad)
    } else if (ph == 2) {
        P.FL = 6; P.GAP = 3;                        // window [0,5] u [9,14], 512B rows
        addg(P.s, 6, 3, 1,0, 1,1, 1,2);             // stage-in fused
        addg(P.s, 6, 3, 1,3, 1,4, 1,5);
        addg(P.s, 6, 3, 1,10, 1,11, 1,12);
        addg(P.s, 6, 3, 2,11, 2,12, 2,13);
        addg(P.s, 6, 3, 3,12, 3,13, 3,14);          // stage-out fused
    } else {
        P.FL = 12; P.GAP = 8;                       // window [0,11]
        addg(P.s, 12, 8, 1,6, 1,7, 1,8);            // stage-in fused
        addg(P.s, 12, 8, 1,9, 2,0, 2,1);
        addg(P.s, 12, 8, 2,2, 2,3, 2,4);
        addg(P.s, 12, 8, 2,5, 2,6, 2,7);
        addg(P.s, 12, 8, 2,8, 2,9, 2,10);
        addg(P.s, 12, 8, 3,3, 3,4, 3,5);
        addg(P.s, 12, 8, 3,6, 3,7, 3,8);
        addg(P.s, 12, 8, 3,9, 3,10, 3,11);
        addg(P.s, 12, 8, 3,0, 3,1, 3,2);            // stage-out fused -> out scatter
    }
    return P;
}

__device__ __forceinline__ unsigned swz(unsigned t) { return t ^ ((t >> 5) & 0xFu); }
__device__ __forceinline__ f32x2 splat2(float x) { f32x2 r = {x, x}; return r; }

template<int FL, int GAP>
__device__ __forceinline__ unsigned gmapF(unsigned t, unsigned mid) {
    if constexpr (FL == 12) return (mid << 12) | t;
    else return (t & ((1u << FL) - 1u)) | ((mid & ((1u << GAP) - 1u)) << FL)
              | ((t >> FL) << (FL + GAP)) | ((mid >> GAP) << (GAP + 12));
}

__device__ __forceinline__ unsigned expand3(unsigned u, int p0, int p1, int p2) {
    u = ((u >> p0) << (p0 + 1)) | (u & ((1u << p0) - 1u));
    u = ((u >> p1) << (p1 + 1)) | (u & ((1u << p1) - 1u));
    u = ((u >> p2) << (p2 + 1)) | (u & ((1u << p2) - 1u));
    return u;
}

__constant__ __device__ int BASE_TBL[3][4] = {{0, 2, 4, 6}, {0, 1, 4, 5}, {0, 1, 2, 3}};

// 3 butterflies on an 8-amp register coset. G must constant-fold.
#define APPLY_GROUP(G, v, g0, cd, sd)                                           \
    {                                                                            \
        _Pragma("unroll")                                                        \
        for (int j = 0; j < 3; ++j) {                                            \
            if ((G).gt[j].valid) {                                               \
                const f32x2 cc_ = splat2((cd)[j]);                               \
                const unsigned par_ = (unsigned)__popc((g0) & (G).gt[j].R) & 1u; \
                const float sp_ = par_ ? (sd)[j] : -(sd)[j];                     \
                _Pragma("unroll")                                                \
                for (int pr = 0; pr < 4; ++pr) {                                 \
                    const int ea = BASE_TBL[j][pr];                              \
                    const int eb = ea | (1 << j);                                \
                    const f32x2 sg_ = splat2((((G).gt[j].sb >> ea) & 1u) ? -sp_ : sp_); \
                    const f32x2 a_ = v[ea], b_ = v[eb];                          \
                    v[ea] = cc_ * a_ + sg_ * b_;                                 \
                    v[eb] = cc_ * b_ - sg_ * a_;                                 \
                }                                                                \
            }                                                                    \
        }                                                                        \
    }

// ================= phase kernel =================
// 4096-amp LDS tile; 512 threads x 8-amp cosets; first/last group fused
// into global stage-in/stage-out.
template<int PH, bool IS_INIT, bool IS_FINAL>
__global__ __launch_bounds__(512) void k_phase(f32x2* __restrict__ st,
                                               const float* __restrict__ qr,
                                               const float* __restrict__ qi,
                                               const float* __restrict__ theta,
                                               float* __restrict__ out) {
    constexpr PhC P = mk_phase(PH);
    constexpr int FL = P.FL, GAP = P.GAP, NG = P.s.ng;
    __shared__ __align__(16) f32x2 lds[4096];
    __shared__ float2 trigS[80];
    const unsigned tid = threadIdx.x;
    const unsigned mid = blockIdx.x;

    if (tid < 80) {
        int l = tid / NQ, b = tid % NQ;
        float th = 0.5f * theta[l * NQ + (NQ - 1 - b)];
        trigS[tid] = make_float2(cosf(th), sinf(th));
    }

    // ---- stage-in, fused group 0 ----
    {
        constexpr GroupC G = P.s.g[0];
        const unsigned t0 = expand3(tid, G.pv[0], G.pv[1], G.pv[2]);
        const unsigned g0 = gmapF<FL, GAP>(t0, mid);
        f32x2 v[8];
        if constexpr (IS_INIT) {
            // group 0 spans bits {0,1,2} -> 8 contiguous amps; planar input
            const f32x4* r4 = reinterpret_cast<const f32x4*>(qr);
            const f32x4* i4 = reinterpret_cast<const f32x4*>(qi);
            f32x4 ra = r4[g0 >> 2], rb = r4[(g0 >> 2) + 1];
            f32x4 ia = i4[g0 >> 2], ib = i4[(g0 >> 2) + 1];
            const float re[8] = {ra.x, ra.y, ra.z, ra.w, rb.x, rb.y, rb.z, rb.w};
            const float im[8] = {ia.x, ia.y, ia.z, ia.w, ib.x, ib.y, ib.z, ib.w};
#pragma unroll
            for (int e = 0; e < 8; ++e) v[e] = f32x2{re[G.gxs[e]], im[G.gxs[e]]};
        } else {
#pragma unroll
            for (int e = 0; e < 8; ++e) v[e] = st[g0 ^ G.gxs[e]];
        }
        float cd[3], sd[3];
#pragma unroll
        for (int j = 0; j < 3; ++j)
            if (G.gt[j].valid) {
                float th = 0.5f * theta[G.gt[j].thix];
                cd[j] = cosf(th); sd[j] = sinf(th);
            }
        APPLY_GROUP(G, v, g0, cd, sd);
#pragma unroll
        for (int e = 0; e < 8; ++e) lds[swz(t0 ^ G.lgxs[e])] = v[e];
    }
    __syncthreads();

    // ---- in-LDS rounds: groups 1 .. NG-2 ----
#pragma unroll
    for (int gi = 1; gi < NG - 1; ++gi) {
        const unsigned t0 = expand3(tid, P.s.g[gi].pv[0], P.s.g[gi].pv[1], P.s.g[gi].pv[2]);
        const unsigned g0 = gmapF<FL, GAP>(t0, mid);
        const unsigned sz0 = swz(t0);
        f32x2 v[8]; unsigned ad[8];
#pragma unroll
        for (int e = 0; e < 8; ++e) {
            ad[e] = sz0 ^ cswz(P.s.g[gi].lgxs[e]);   // folds to immediate XOR
            v[e] = lds[ad[e]];
        }
        float cd[3], sd[3];
#pragma unroll
        for (int j = 0; j < 3; ++j)
            if (P.s.g[gi].gt[j].valid) {
                float2 cs = trigS[P.s.g[gi].gt[j].tix];
                cd[j] = cs.x; sd[j] = cs.y;
            }
        APPLY_GROUP(P.s.g[gi], v, g0, cd, sd);
#pragma unroll
        for (int e = 0; e < 8; ++e) lds[ad[e]] = v[e];
        __syncthreads();
    }

    // ---- stage-out, fused group NG-1 ----
    {
        constexpr GroupC G = P.s.g[NG - 1];
        const unsigned t0 = expand3(tid, G.pv[0], G.pv[1], G.pv[2]);
        const unsigned g0 = gmapF<FL, GAP>(t0, mid);
        f32x2 v[8];
#pragma unroll
        for (int e = 0; e < 8; ++e) v[e] = lds[swz(t0 ^ G.lgxs[e])];
        float cd[3], sd[3];
#pragma unroll
        for (int j = 0; j < 3; ++j)
            if (G.gt[j].valid) {
                float2 cs = trigS[G.gt[j].tix];
                cd[j] = cs.x; sd[j] = cs.y;
            }
        APPLY_GROUP(G, v, g0, cd, sd);
        if constexpr (IS_FINAL) {
            // inverse-Gray gather + planar split; group spans bits {0,1,2},
            // so i(e) = i0 ^ gxs[e] with i0 = ginv4(g0).
            const unsigned i0 = g0 ^ (g0 >> 4) ^ (g0 >> 8) ^ (g0 >> 12) ^ (g0 >> 16);
#pragma unroll
            for (int e = 0; e < 8; ++e) {
                const unsigned i = i0 ^ G.gxs[e];
                out[i] = v[e].x;
                out[DIM + i] = v[e].y;
            }
        } else {
#pragma unroll
            for (int e = 0; e < 8; ++e) st[g0 ^ G.gxs[e]] = v[e];
        }
    }
}

// ================= launch =================
extern "C" void kernel_launch(void* const* d_in, const int* in_sizes, int n_in,
                              void* d_out, int out_size, void* d_ws, size_t ws_size,
                              hipStream_t stream) {
    const float* theta = (const float*)d_in[0];   // (4,20) float32
    const float* qr    = (const float*)d_in[1];
    const float* qi    = (const float*)d_in[2];
    float* out = (float*)d_out;
    f32x2* st = (f32x2*)d_ws;                     // 8 MiB interleaved state

    k_phase<0, true,  false><<<256, 512, 0, stream>>>(st, qr, qi, theta, out);
    k_phase<1, false, false><<<256, 512, 0, stream>>>(st, qr, qi, theta, out);
    k_phase<2, false, false><<<256, 512, 0, stream>>>(st, qr, qi, theta, out);
    k_phase<3, false, true ><<<256, 512, 0, stream>>>(st, qr, qi, theta, out);
}